// Round 7
// baseline (435.949 us; speedup 1.0000x reference)
//
#include <hip/hip_runtime.h>
#include <math.h>

#define BB 65536
#define ND 8

typedef float f4 __attribute__((ext_vector_type(4)));
typedef float f32x4 __attribute__((ext_vector_type(4)));
typedef _Float16 half8 __attribute__((ext_vector_type(8)));
typedef __fp16 fp16x2 __attribute__((ext_vector_type(2)));   // return type of cvt_pkrtz

// d_ws: weights in MFMA-FRAGMENT ORDER. One record = 512 f16 (1 KiB): lane l's
// 8 f16 at record + l*8. Record pairs: [hi][lo] adjacent (stride 512 f16).
//   F1: rec = (i*16 + nt)*2 + p            nt=0..15  -> n=nt*16+li, k=lg4*8+j
//   F2: rec = ((i*8+ks)*16 + nt)*2 + p     ks=0..7   -> k=ks*32+lg4*8+j
//   F3: rec = ((i*8+ks)*4  + nt)*2 + p     nt=0..3 (n<64)
#define F1_OFF 0
#define F2_OFF 131072
#define F3_OFF 1179648
#define WTOT_F16 1441792   // = 2,883,584 bytes

#define MFMA16(a, b, c) __builtin_amdgcn_mfma_f32_16x16x32_f16((a), (b), (c), 0, 0, 0)

// ---------- weight transpose + hi/lo split into fragment order ----------
__global__ __launch_bounds__(256)
void prep_weights(const float* __restrict__ W1, const float* __restrict__ W2,
                  const float* __restrict__ Wf, _Float16* __restrict__ wt)
{
    int t = blockIdx.x * 256 + threadIdx.x;   // dest f16 index; grid covers exactly WTOT_F16
    float wv;
    int p;
    if (t < F2_OFF) {                         // W1 frags
        int rec = t >> 9, off = t & 511;
        p = rec & 1;
        int nt = (rec >> 1) & 15, i = rec >> 5;
        int l = off >> 3, j = off & 7;
        int n = nt*16 + (l & 15), k = (l >> 4)*8 + j;
        wv = W1[i*8192 + k*256 + n];
    } else if (t < F3_OFF) {                  // W2 frags
        int u = t - F2_OFF;
        int rec = u >> 9, off = u & 511;
        p = rec & 1;
        int nt = (rec >> 1) & 15, ks = (rec >> 5) & 7, i = rec >> 8;
        int l = off >> 3, j = off & 7;
        int n = nt*16 + (l & 15), k = ks*32 + (l >> 4)*8 + j;
        wv = W2[i*65536 + k*256 + n];
    } else {                                  // Wf frags
        int u = t - F3_OFF;
        int rec = u >> 9, off = u & 511;
        p = rec & 1;
        int nt = (rec >> 1) & 3, ks = (rec >> 3) & 7, i = rec >> 6;
        int l = off >> 3, j = off & 7;
        int n = nt*16 + (l & 15), k = ks*32 + (l >> 4)*8 + j;
        wv = Wf[i*16384 + k*64 + n];
    }
    _Float16 hi = (_Float16)wv;
    wt[t] = p ? (_Float16)(wv - (float)hi) : hi;
}

// split 8 fp32 -> f16 hi + f16 lo fragments (k-ascending).
__device__ __forceinline__ void split8(f4 a, f4 b, half8& hi, half8& lo)
{
    union U { half8 v; fp16x2 h[4]; } H, L;
    H.h[0] = __builtin_amdgcn_cvt_pkrtz(a[0], a[1]);
    H.h[1] = __builtin_amdgcn_cvt_pkrtz(a[2], a[3]);
    H.h[2] = __builtin_amdgcn_cvt_pkrtz(b[0], b[1]);
    H.h[3] = __builtin_amdgcn_cvt_pkrtz(b[2], b[3]);
    L.h[0] = __builtin_amdgcn_cvt_pkrtz(a[0] - (float)H.h[0][0], a[1] - (float)H.h[0][1]);
    L.h[1] = __builtin_amdgcn_cvt_pkrtz(a[2] - (float)H.h[1][0], a[3] - (float)H.h[1][1]);
    L.h[2] = __builtin_amdgcn_cvt_pkrtz(b[0] - (float)H.h[2][0], b[1] - (float)H.h[2][1]);
    L.h[3] = __builtin_amdgcn_cvt_pkrtz(b[2] - (float)H.h[3][0], b[3] - (float)H.h[3][1]);
    hi = H.v; lo = L.v;
}

// fast tanh: 1 - 2/(e^{2|x|}+1), sign restored. Graceful at |x| large (e->inf -> t->1).
__device__ __forceinline__ float fast_tanh(float x)
{
    float e = __expf(2.0f * fabsf(x));
    float t = 1.0f - 2.0f / (e + 1.0f);
    return copysignf(t, x);
}

// Fused 8-layer flow. 32 rows/block, 4 waves each owning 32 rows x 64 n.
// LDS 40KB -> 4 blocks/CU (4 waves/SIMD).
// zb: fp32 [32][64], hb: fp32 [32][256]; XOR-swizzled per f4 block:
//   elem (r,c) at  r*W + ((c>>2) ^ (r&7))*4 + (c&3)
// MFMA: A = weight frag (global, fragment-ordered, coalesced), B = activation rows
// (k-contig, LDS) -> D[n][batchrow]; lane holds 4 consecutive n for one row.
__global__ __launch_bounds__(256, 4)
void flow_mfma(const float* __restrict__ x,
               const float* __restrict__ logdet_in,
               const float* __restrict__ bP,
               const float* __restrict__ logsP,
               const float* __restrict__ b1P,
               const float* __restrict__ b2P,
               const float* __restrict__ bfP,
               const float* __restrict__ lgP,
               const _Float16* __restrict__ wt,
               float* __restrict__ out)
{
    __shared__ float zb[32 * 64];    // 8 KB
    __shared__ float hb[32 * 256];   // 32 KB  (reused as logdet scratch at end)

    const int tid  = threadIdx.x;
    const int w    = tid >> 6;        // wave id 0..3 = n-slice owner
    const int lane = tid & 63;
    const int li   = lane & 15;
    const int lg4  = lane >> 4;
    const int row0 = blockIdx.x * 32;

    // scalar sum of ALL logs (same for every row) -- per-thread, no LDS
    float lsum;
    {
        float s = 0.f;
        #pragma unroll
        for (int i2 = 0; i2 < 8; ++i2) s += logsP[i2*64 + lane];
        s += __shfl_xor(s, 1);  s += __shfl_xor(s, 2);  s += __shfl_xor(s, 4);
        s += __shfl_xor(s, 8);  s += __shfl_xor(s, 16); s += __shfl_xor(s, 32);
        lsum = s;
    }

    // load z tile (swizzled): 32x64 = 512 f4, 2 per thread
    {
        const f4* xs = (const f4*)(x + (size_t)row0 * 64);
        #pragma unroll
        for (int q = 0; q < 2; ++q) {
            int idx4 = tid + q*256;
            int r = idx4 >> 4, cf = idx4 & 15;
            *(f4*)&zb[r*64 + ((cf ^ (r & 7)) << 2)] = xs[idx4];
        }
    }

    const int rA = li;          // this lane's two batch rows
    const int rB = 16 + li;
    const int s8 = li & 7;      // swizzle key; same for rA and rB

    float ldp0 = 0.f, ldp1 = 0.f;
    const f32x4 zero4 = {0.f, 0.f, 0.f, 0.f};

    #pragma unroll 1
    for (int i = 0; i < ND; ++i) {
        __syncthreads();   // covers z-load (iter 0) and reversal (iters >0)

        // ---- affine: z = (z + b) * exp(logs) ----
        #pragma unroll
        for (int q = 0; q < 2; ++q) {
            int idx4 = tid + q*256;
            int r = idx4 >> 4, cf = idx4 & 15;
            float* zp = &zb[r*64 + ((cf ^ (r & 7)) << 2)];
            f4 z  = *(f4*)zp;
            f4 bv = *(const f4*)&bP[i*64 + cf*4];
            f4 lv = *(const f4*)&logsP[i*64 + cf*4];
            f4 ev = { __expf(lv[0]), __expf(lv[1]), __expf(lv[2]), __expf(lv[3]) };
            z = (z + bv) * ev;
            *(f4*)zp = z;
        }
        __syncthreads();

        // ---- GEMM1: h1 = relu(z1 @ W1 + b1)  (K=32, one k-step) ----
        {
            half8 bh0, bl0, bh1, bl1;
            {
                int cf = lg4 * 2;
                f4 a0 = *(const f4*)&zb[rA*64 + (((cf    ) ^ s8) << 2)];
                f4 a1 = *(const f4*)&zb[rA*64 + (((cf + 1) ^ s8) << 2)];
                split8(a0, a1, bh0, bl0);
                f4 c0 = *(const f4*)&zb[rB*64 + (((cf    ) ^ s8) << 2)];
                f4 c1 = *(const f4*)&zb[rB*64 + (((cf + 1) ^ s8) << 2)];
                split8(c0, c1, bh1, bl1);
            }
            f32x4 acc[4][2];
            #pragma unroll
            for (int nt = 0; nt < 4; ++nt) { acc[nt][0] = zero4; acc[nt][1] = zero4; }
            const _Float16* w1f = wt + F1_OFF + i*16384 + lane*8;
            #pragma unroll
            for (int nt = 0; nt < 4; ++nt) {
                const _Float16* fb = w1f + (w*4 + nt)*1024;
                half8 ah = *(const half8*)fb;
                half8 al = *(const half8*)(fb + 512);
                acc[nt][0] = MFMA16(ah, bh0, acc[nt][0]);
                acc[nt][1] = MFMA16(ah, bh1, acc[nt][1]);
                acc[nt][0] = MFMA16(ah, bl0, acc[nt][0]);
                acc[nt][1] = MFMA16(ah, bl1, acc[nt][1]);
                acc[nt][0] = MFMA16(al, bh0, acc[nt][0]);
                acc[nt][1] = MFMA16(al, bh1, acc[nt][1]);
            }
            const float* bb = b1P + i*256;
            #pragma unroll
            for (int nt = 0; nt < 4; ++nt) {
                int n0 = w*64 + nt*16 + lg4*4;
                f4 bias = *(const f4*)&bb[n0];
                int cfw = n0 >> 2;
                #pragma unroll
                for (int rt = 0; rt < 2; ++rt) {
                    int r = rt ? rB : rA;
                    f4 v = acc[nt][rt] + bias;
                    v[0] = fmaxf(v[0], 0.f); v[1] = fmaxf(v[1], 0.f);
                    v[2] = fmaxf(v[2], 0.f); v[3] = fmaxf(v[3], 0.f);
                    *(f4*)&hb[r*256 + ((cfw ^ s8) << 2)] = v;
                }
            }
        }
        __syncthreads();

        // ---- GEMM2: h2 = relu(h1 @ W2 + b2)  (K=256) ----
        {
            f32x4 acc[4][2];
            #pragma unroll
            for (int nt = 0; nt < 4; ++nt) { acc[nt][0] = zero4; acc[nt][1] = zero4; }
            const _Float16* w2f = wt + F2_OFF + i*131072 + lane*8;
            #pragma unroll 2
            for (int ks = 0; ks < 8; ++ks) {
                int cf = ks*8 + lg4*2;
                half8 ph0, pl0, ph1, pl1;
                f4 a0 = *(const f4*)&hb[rA*256 + (((cf    ) ^ s8) << 2)];
                f4 a1 = *(const f4*)&hb[rA*256 + (((cf + 1) ^ s8) << 2)];
                split8(a0, a1, ph0, pl0);
                f4 c0 = *(const f4*)&hb[rB*256 + (((cf    ) ^ s8) << 2)];
                f4 c1 = *(const f4*)&hb[rB*256 + (((cf + 1) ^ s8) << 2)];
                split8(c0, c1, ph1, pl1);
                const _Float16* wk = w2f + ks*16384;
                #pragma unroll
                for (int nt = 0; nt < 4; ++nt) {
                    const _Float16* fb = wk + (w*4 + nt)*1024;
                    half8 ah = *(const half8*)fb;
                    half8 al = *(const half8*)(fb + 512);
                    acc[nt][0] = MFMA16(ah, ph0, acc[nt][0]);
                    acc[nt][1] = MFMA16(ah, ph1, acc[nt][1]);
                    acc[nt][0] = MFMA16(ah, pl0, acc[nt][0]);
                    acc[nt][1] = MFMA16(ah, pl1, acc[nt][1]);
                    acc[nt][0] = MFMA16(al, ph0, acc[nt][0]);
                    acc[nt][1] = MFMA16(al, ph1, acc[nt][1]);
                }
            }
            __syncthreads();   // all h1 reads done before overwrite
            const float* bb = b2P + i*256;
            #pragma unroll
            for (int nt = 0; nt < 4; ++nt) {
                int n0 = w*64 + nt*16 + lg4*4;
                f4 bias = *(const f4*)&bb[n0];
                int cfw = n0 >> 2;
                #pragma unroll
                for (int rt = 0; rt < 2; ++rt) {
                    int r = rt ? rB : rA;
                    f4 v = acc[nt][rt] + bias;
                    v[0] = fmaxf(v[0], 0.f); v[1] = fmaxf(v[1], 0.f);
                    v[2] = fmaxf(v[2], 0.f); v[3] = fmaxf(v[3], 0.f);
                    *(f4*)&hb[r*256 + ((cfw ^ s8) << 2)] = v;
                }
            }
        }
        __syncthreads();

        // ---- GEMM3: h3 = h2 @ Wf + bf  -> gated z2 update + logdet ----
        {
            f32x4 acc3[2];
            acc3[0] = zero4; acc3[1] = zero4;
            const _Float16* w3f = wt + F3_OFF + i*32768 + lane*8;
            #pragma unroll 2
            for (int ks = 0; ks < 8; ++ks) {
                int cf = ks*8 + lg4*2;
                half8 ph0, pl0, ph1, pl1;
                f4 a0 = *(const f4*)&hb[rA*256 + (((cf    ) ^ s8) << 2)];
                f4 a1 = *(const f4*)&hb[rA*256 + (((cf + 1) ^ s8) << 2)];
                split8(a0, a1, ph0, pl0);
                f4 c0 = *(const f4*)&hb[rB*256 + (((cf    ) ^ s8) << 2)];
                f4 c1 = *(const f4*)&hb[rB*256 + (((cf + 1) ^ s8) << 2)];
                split8(c0, c1, ph1, pl1);
                const _Float16* fb = w3f + ks*4096 + w*1024;
                half8 ah = *(const half8*)fb;
                half8 al = *(const half8*)(fb + 512);
                acc3[0] = MFMA16(ah, ph0, acc3[0]);
                acc3[1] = MFMA16(ah, ph1, acc3[1]);
                acc3[0] = MFMA16(ah, pl0, acc3[0]);
                acc3[1] = MFMA16(ah, pl1, acc3[1]);
                acc3[0] = MFMA16(al, ph0, acc3[0]);
                acc3[1] = MFMA16(al, ph1, acc3[1]);
            }
            // epilogue: lane holds (shift,scale) pairs for 2 j-values x 2 rows
            {
                int n0 = w*16 + lg4*4;
                int j0 = n0 >> 1;
                f4 bias = *(const f4*)&bfP[i*64 + n0];
                float eg0 = __expf(lgP[i*32 + j0]);
                float eg1 = __expf(lgP[i*32 + j0 + 1]);
                #pragma unroll
                for (int rt = 0; rt < 2; ++rt) {
                    int r = rt ? rB : rA;
                    f4 v = acc3[rt];
                    float sh0 = eg0  * fast_tanh(v[0] + bias[0]);
                    float sc0 = 0.6f * fast_tanh(v[1] + bias[1]);
                    float sh1 = eg1  * fast_tanh(v[2] + bias[2]);
                    float sc1 = 0.6f * fast_tanh(v[3] + bias[3]);
                    int c = 32 + j0;                       // j0, j0+1 share an f4 block
                    int addr = r*64 + ((((c >> 2) ^ s8)) << 2) + (c & 3);
                    float z0  = zb[addr];
                    float z1v = zb[addr + 1];
                    zb[addr]     = fmaf(sc0, z0,  z0  + sh0);
                    zb[addr + 1] = fmaf(sc1, z1v, z1v + sh1);
                    float l01 = __logf(1.0f + sc0) + __logf(1.0f + sc1);
                    if (rt == 0) ldp0 += l01; else ldp1 += l01;
                }
            }
        }
        __syncthreads();

        // ---- reversal: z = z[:, ::-1] (logical f4-block pair swap); 256 tasks ----
        {
            int r = tid >> 3, cfL = tid & 7;
            int s = r & 7;
            float* pL = &zb[r*64 + ((cfL ^ s) << 2)];
            float* pR = &zb[r*64 + (((15 - cfL) ^ s) << 2)];
            f4 Lv = *(f4*)pL;
            f4 Rv = *(f4*)pR;
            f4 nL = { Rv[3], Rv[2], Rv[1], Rv[0] };
            f4 nR = { Lv[3], Lv[2], Lv[1], Lv[0] };
            *(f4*)pL = nL;
            *(f4*)pR = nR;
        }
    }
    __syncthreads();

    // ---- store z ----
    {
        f4* oz = (f4*)(out + (size_t)row0 * 64);
        #pragma unroll
        for (int q = 0; q < 2; ++q) {
            int idx4 = tid + q*256;
            int r = idx4 >> 4, cf = idx4 & 15;
            oz[idx4] = *(const f4*)&zb[r*64 + ((cf ^ (r & 7)) << 2)];
        }
    }

    // ---- logdet: reduce ldp over lg4 groups, combine 4 wave-slices via hb scratch ----
    float v0 = ldp0 + __shfl_xor(ldp0, 16); v0 += __shfl_xor(v0, 32);
    float v1 = ldp1 + __shfl_xor(ldp1, 16); v1 += __shfl_xor(v1, 32);
    if (lg4 == 0) {
        hb[rA*4 + w] = v0;
        hb[rB*4 + w] = v1;
    }
    __syncthreads();
    if (tid < 32) {
        int gr = row0 + tid;
        out[(size_t)BB * 64 + gr] = logdet_in[gr] + lsum
                                  + hb[tid*4] + hb[tid*4+1] + hb[tid*4+2] + hb[tid*4+3];
    }
}

extern "C" void kernel_launch(void* const* d_in, const int* in_sizes, int n_in,
                              void* d_out, int out_size, void* d_ws, size_t ws_size,
                              hipStream_t stream)
{
    const float* x    = (const float*)d_in[0];
    const float* ld   = (const float*)d_in[1];
    const float* b    = (const float*)d_in[2];
    const float* logs = (const float*)d_in[3];
    const float* W1   = (const float*)d_in[4];
    const float* b1   = (const float*)d_in[5];
    const float* W2   = (const float*)d_in[6];
    const float* b2   = (const float*)d_in[7];
    const float* Wf   = (const float*)d_in[8];
    const float* bf   = (const float*)d_in[9];
    const float* lg   = (const float*)d_in[10];
    _Float16* wt = (_Float16*)d_ws;
    float* out = (float*)d_out;

    prep_weights<<<WTOT_F16 / 256, 256, 0, stream>>>(W1, W2, Wf, wt);
    flow_mfma<<<2048, 256, 0, stream>>>(x, ld, b, logs, b1, b2, bf, lg, wt, out);
}

// Round 9
// 389.391 us; speedup vs baseline: 1.1196x; 1.1196x over previous
//
#include <hip/hip_runtime.h>
#include <math.h>

#define BB 65536
#define ND 8

typedef float f4 __attribute__((ext_vector_type(4)));
typedef float f32x4 __attribute__((ext_vector_type(4)));
typedef _Float16 half8 __attribute__((ext_vector_type(8)));
typedef _Float16 half4 __attribute__((ext_vector_type(4)));
typedef __fp16 fp16x2 __attribute__((ext_vector_type(2)));   // return type of cvt_pkrtz

// d_ws: weights in MFMA-FRAGMENT ORDER. One record = 512 f16 (1 KiB): lane l's
// 8 f16 at record + l*8. Record pairs: [hi][lo] adjacent (stride 512 f16).
#define F1_OFF 0
#define F2_OFF 131072
#define F3_OFF 1179648
#define WTOT_F16 1441792   // = 2,883,584 bytes

#define MFMA16(a, b, c) __builtin_amdgcn_mfma_f32_16x16x32_f16((a), (b), (c), 0, 0, 0)

// ---------- weight transpose + hi/lo split into fragment order ----------
__global__ __launch_bounds__(256)
void prep_weights(const float* __restrict__ W1, const float* __restrict__ W2,
                  const float* __restrict__ Wf, _Float16* __restrict__ wt)
{
    int t = blockIdx.x * 256 + threadIdx.x;   // dest f16 index; grid covers exactly WTOT_F16
    float wv;
    int p;
    if (t < F2_OFF) {                         // W1 frags
        int rec = t >> 9, off = t & 511;
        p = rec & 1;
        int nt = (rec >> 1) & 15, i = rec >> 5;
        int l = off >> 3, j = off & 7;
        int n = nt*16 + (l & 15), k = (l >> 4)*8 + j;
        wv = W1[i*8192 + k*256 + n];
    } else if (t < F3_OFF) {                  // W2 frags
        int u = t - F2_OFF;
        int rec = u >> 9, off = u & 511;
        p = rec & 1;
        int nt = (rec >> 1) & 15, ks = (rec >> 5) & 7, i = rec >> 8;
        int l = off >> 3, j = off & 7;
        int n = nt*16 + (l & 15), k = ks*32 + (l >> 4)*8 + j;
        wv = W2[i*65536 + k*256 + n];
    } else {                                  // Wf frags
        int u = t - F3_OFF;
        int rec = u >> 9, off = u & 511;
        p = rec & 1;
        int nt = (rec >> 1) & 3, ks = (rec >> 3) & 7, i = rec >> 6;
        int l = off >> 3, j = off & 7;
        int n = nt*16 + (l & 15), k = ks*32 + (l >> 4)*8 + j;
        wv = Wf[i*16384 + k*64 + n];
    }
    _Float16 hi = (_Float16)wv;
    wt[t] = p ? (_Float16)(wv - (float)hi) : hi;
}

// split 8 fp32 -> f16 hi + f16 lo fragments (k-ascending). Used only for z1 (GEMM1 B).
__device__ __forceinline__ void split8(f4 a, f4 b, half8& hi, half8& lo)
{
    union U { half8 v; fp16x2 h[4]; } H, L;
    H.h[0] = __builtin_amdgcn_cvt_pkrtz(a[0], a[1]);
    H.h[1] = __builtin_amdgcn_cvt_pkrtz(a[2], a[3]);
    H.h[2] = __builtin_amdgcn_cvt_pkrtz(b[0], b[1]);
    H.h[3] = __builtin_amdgcn_cvt_pkrtz(b[2], b[3]);
    L.h[0] = __builtin_amdgcn_cvt_pkrtz(a[0] - (float)H.h[0][0], a[1] - (float)H.h[0][1]);
    L.h[1] = __builtin_amdgcn_cvt_pkrtz(a[2] - (float)H.h[1][0], a[3] - (float)H.h[1][1]);
    L.h[2] = __builtin_amdgcn_cvt_pkrtz(b[0] - (float)H.h[2][0], b[1] - (float)H.h[2][1]);
    L.h[3] = __builtin_amdgcn_cvt_pkrtz(b[2] - (float)H.h[3][0], b[3] - (float)H.h[3][1]);
    hi = H.v; lo = L.v;
}

// split 4 fp32 -> 4 f16 hi + 4 f16 lo and store 8B to each plane (once per element!)
__device__ __forceinline__ void store_split4(f4 v, _Float16* ph, _Float16* pl)
{
    union U { half4 v4; fp16x2 h[2]; } H, L;
    H.h[0] = __builtin_amdgcn_cvt_pkrtz(v[0], v[1]);
    H.h[1] = __builtin_amdgcn_cvt_pkrtz(v[2], v[3]);
    L.h[0] = __builtin_amdgcn_cvt_pkrtz(v[0] - (float)H.h[0][0], v[1] - (float)H.h[0][1]);
    L.h[1] = __builtin_amdgcn_cvt_pkrtz(v[2] - (float)H.h[1][0], v[3] - (float)H.h[1][1]);
    *(half4*)ph = H.v4;
    *(half4*)pl = L.v4;
}

// fast tanh: 1 - 2/(e^{2|x|}+1), sign restored.
__device__ __forceinline__ float fast_tanh(float x)
{
    float e = __expf(2.0f * fabsf(x));
    float t = 1.0f - 2.0f / (e + 1.0f);
    return copysignf(t, x);
}

// Fused 8-layer flow. 32 rows/block, 4 waves each owning 32 rows x 64 n.
// LDS 40KB -> 4 blocks/CU.
// zb: fp32 [32][64], f4-block swizzled: elem (r,c) at r*64 + ((c>>2)^(r&7))*4 + (c&3).
// hbf: TWO f16 planes [hi][lo], each [32][256], granule(8 f16)-swizzled:
//   granule g of row r stored at f16 index r*256 + (g^(r&7))*8.
//   Written pre-split by epilogues (store_split4) -> GEMM2/3 read MFMA B-fragments
//   directly with ds_read_b128, ZERO VALU between LDS read and MFMA.
__global__ __launch_bounds__(256, 4)
void flow_mfma(const float* __restrict__ x,
               const float* __restrict__ logdet_in,
               const float* __restrict__ bP,
               const float* __restrict__ logsP,
               const float* __restrict__ b1P,
               const float* __restrict__ b2P,
               const float* __restrict__ bfP,
               const float* __restrict__ lgP,
               const _Float16* __restrict__ wt,
               float* __restrict__ out)
{
    __shared__ float zb[32 * 64];          // 8 KB
    __shared__ _Float16 hbf[2][32 * 256];  // 32 KB: [0]=hi plane, [1]=lo plane

    const int tid  = threadIdx.x;
    const int w    = tid >> 6;        // wave id 0..3 = n-slice owner
    const int lane = tid & 63;
    const int li   = lane & 15;
    const int lg4  = lane >> 4;
    const int row0 = blockIdx.x * 32;

    // scalar sum of ALL logs (same for every row)
    float lsum;
    {
        float s = 0.f;
        #pragma unroll
        for (int i2 = 0; i2 < 8; ++i2) s += logsP[i2*64 + lane];
        s += __shfl_xor(s, 1);  s += __shfl_xor(s, 2);  s += __shfl_xor(s, 4);
        s += __shfl_xor(s, 8);  s += __shfl_xor(s, 16); s += __shfl_xor(s, 32);
        lsum = s;
    }

    // load z tile (swizzled): 32x64 = 512 f4, 2 per thread
    {
        const f4* xs = (const f4*)(x + (size_t)row0 * 64);
        #pragma unroll
        for (int q = 0; q < 2; ++q) {
            int idx4 = tid + q*256;
            int r = idx4 >> 4, cf = idx4 & 15;
            *(f4*)&zb[r*64 + ((cf ^ (r & 7)) << 2)] = xs[idx4];
        }
    }

    const int rA = li;          // this lane's two batch rows
    const int rB = 16 + li;
    const int s8 = li & 7;      // swizzle key; same for rA and rB

    float ldp0 = 0.f, ldp1 = 0.f;
    const f32x4 zero4 = {0.f, 0.f, 0.f, 0.f};

    #pragma unroll 1
    for (int i = 0; i < ND; ++i) {
        __syncthreads();   // covers z-load (iter 0) and reversal (iters >0)

        // ---- affine: z = (z + b) * exp(logs) ----
        #pragma unroll
        for (int q = 0; q < 2; ++q) {
            int idx4 = tid + q*256;
            int r = idx4 >> 4, cf = idx4 & 15;
            float* zp = &zb[r*64 + ((cf ^ (r & 7)) << 2)];
            f4 z  = *(f4*)zp;
            f4 bv = *(const f4*)&bP[i*64 + cf*4];
            f4 lv = *(const f4*)&logsP[i*64 + cf*4];
            f4 ev = { __expf(lv[0]), __expf(lv[1]), __expf(lv[2]), __expf(lv[3]) };
            z = (z + bv) * ev;
            *(f4*)zp = z;
        }
        __syncthreads();

        // ---- GEMM1: h1 = relu(z1 @ W1 + b1)  (K=32, one k-step) ----
        {
            half8 bh0, bl0, bh1, bl1;
            {
                int cf = lg4 * 2;
                f4 a0 = *(const f4*)&zb[rA*64 + (((cf    ) ^ s8) << 2)];
                f4 a1 = *(const f4*)&zb[rA*64 + (((cf + 1) ^ s8) << 2)];
                split8(a0, a1, bh0, bl0);
                f4 c0 = *(const f4*)&zb[rB*64 + (((cf    ) ^ s8) << 2)];
                f4 c1 = *(const f4*)&zb[rB*64 + (((cf + 1) ^ s8) << 2)];
                split8(c0, c1, bh1, bl1);
            }
            f32x4 acc[4][2];
            #pragma unroll
            for (int nt = 0; nt < 4; ++nt) { acc[nt][0] = zero4; acc[nt][1] = zero4; }
            const _Float16* w1f = wt + F1_OFF + i*16384 + lane*8;
            #pragma unroll
            for (int nt = 0; nt < 4; ++nt) {
                const _Float16* fb = w1f + (w*4 + nt)*1024;
                half8 ah = *(const half8*)fb;
                half8 al = *(const half8*)(fb + 512);
                acc[nt][0] = MFMA16(ah, bh0, acc[nt][0]);
                acc[nt][1] = MFMA16(ah, bh1, acc[nt][1]);
                acc[nt][0] = MFMA16(ah, bl0, acc[nt][0]);
                acc[nt][1] = MFMA16(ah, bl1, acc[nt][1]);
                acc[nt][0] = MFMA16(al, bh0, acc[nt][0]);
                acc[nt][1] = MFMA16(al, bh1, acc[nt][1]);
            }
            const float* bb = b1P + i*256;
            #pragma unroll
            for (int nt = 0; nt < 4; ++nt) {
                int n0 = w*64 + nt*16 + lg4*4;
                f4 bias = *(const f4*)&bb[n0];
                int idx = ((n0 >> 3) ^ s8) * 8 + (n0 & 7);   // granule-swizzled
                #pragma unroll
                for (int rt = 0; rt < 2; ++rt) {
                    int r = rt ? rB : rA;
                    f4 v = acc[nt][rt] + bias;
                    v[0] = fmaxf(v[0], 0.f); v[1] = fmaxf(v[1], 0.f);
                    v[2] = fmaxf(v[2], 0.f); v[3] = fmaxf(v[3], 0.f);
                    store_split4(v, &hbf[0][r*256 + idx], &hbf[1][r*256 + idx]);
                }
            }
        }
        __syncthreads();

        // ---- GEMM2: h2 = relu(h1 @ W2 + b2)  (K=256) ----
        {
            f32x4 acc[4][2];
            #pragma unroll
            for (int nt = 0; nt < 4; ++nt) { acc[nt][0] = zero4; acc[nt][1] = zero4; }
            const _Float16* w2f = wt + F2_OFF + i*131072 + lane*8;
            #pragma unroll 2
            for (int ks = 0; ks < 8; ++ks) {
                int kg = (ks*4 + lg4) ^ s8;           // physical granule
                int iA = rA*256 + kg*8;
                int iB = rB*256 + kg*8;
                half8 ph0 = *(const half8*)&hbf[0][iA];
                half8 pl0 = *(const half8*)&hbf[1][iA];
                half8 ph1 = *(const half8*)&hbf[0][iB];
                half8 pl1 = *(const half8*)&hbf[1][iB];
                const _Float16* wk = w2f + ks*16384;
                #pragma unroll
                for (int nt = 0; nt < 4; ++nt) {
                    const _Float16* fb = wk + (w*4 + nt)*1024;
                    half8 ah = *(const half8*)fb;
                    half8 al = *(const half8*)(fb + 512);
                    acc[nt][0] = MFMA16(ah, ph0, acc[nt][0]);
                    acc[nt][1] = MFMA16(ah, ph1, acc[nt][1]);
                    acc[nt][0] = MFMA16(ah, pl0, acc[nt][0]);
                    acc[nt][1] = MFMA16(ah, pl1, acc[nt][1]);
                    acc[nt][0] = MFMA16(al, ph0, acc[nt][0]);
                    acc[nt][1] = MFMA16(al, ph1, acc[nt][1]);
                }
            }
            __syncthreads();   // all h1 reads done before overwrite
            const float* bb = b2P + i*256;
            #pragma unroll
            for (int nt = 0; nt < 4; ++nt) {
                int n0 = w*64 + nt*16 + lg4*4;
                f4 bias = *(const f4*)&bb[n0];
                int idx = ((n0 >> 3) ^ s8) * 8 + (n0 & 7);
                #pragma unroll
                for (int rt = 0; rt < 2; ++rt) {
                    int r = rt ? rB : rA;
                    f4 v = acc[nt][rt] + bias;
                    v[0] = fmaxf(v[0], 0.f); v[1] = fmaxf(v[1], 0.f);
                    v[2] = fmaxf(v[2], 0.f); v[3] = fmaxf(v[3], 0.f);
                    store_split4(v, &hbf[0][r*256 + idx], &hbf[1][r*256 + idx]);
                }
            }
        }
        __syncthreads();

        // ---- GEMM3: h3 = h2 @ Wf + bf  -> gated z2 update + logdet ----
        {
            f32x4 acc3[2];
            acc3[0] = zero4; acc3[1] = zero4;
            const _Float16* w3f = wt + F3_OFF + i*32768 + lane*8;
            #pragma unroll 2
            for (int ks = 0; ks < 8; ++ks) {
                int kg = (ks*4 + lg4) ^ s8;
                int iA = rA*256 + kg*8;
                int iB = rB*256 + kg*8;
                half8 ph0 = *(const half8*)&hbf[0][iA];
                half8 pl0 = *(const half8*)&hbf[1][iA];
                half8 ph1 = *(const half8*)&hbf[0][iB];
                half8 pl1 = *(const half8*)&hbf[1][iB];
                const _Float16* fb = w3f + ks*4096 + w*1024;
                half8 ah = *(const half8*)fb;
                half8 al = *(const half8*)(fb + 512);
                acc3[0] = MFMA16(ah, ph0, acc3[0]);
                acc3[1] = MFMA16(ah, ph1, acc3[1]);
                acc3[0] = MFMA16(ah, pl0, acc3[0]);
                acc3[1] = MFMA16(ah, pl1, acc3[1]);
                acc3[0] = MFMA16(al, ph0, acc3[0]);
                acc3[1] = MFMA16(al, ph1, acc3[1]);
            }
            // epilogue: lane holds (shift,scale) pairs for 2 j-values x 2 rows
            {
                int n0 = w*16 + lg4*4;
                int j0 = n0 >> 1;
                f4 bias = *(const f4*)&bfP[i*64 + n0];
                float eg0 = __expf(lgP[i*32 + j0]);
                float eg1 = __expf(lgP[i*32 + j0 + 1]);
                #pragma unroll
                for (int rt = 0; rt < 2; ++rt) {
                    int r = rt ? rB : rA;
                    f4 v = acc3[rt];
                    float sh0 = eg0  * fast_tanh(v[0] + bias[0]);
                    float sc0 = 0.6f * fast_tanh(v[1] + bias[1]);
                    float sh1 = eg1  * fast_tanh(v[2] + bias[2]);
                    float sc1 = 0.6f * fast_tanh(v[3] + bias[3]);
                    int c = 32 + j0;                       // j0, j0+1 share an f4 block
                    int addr = r*64 + ((((c >> 2) ^ s8)) << 2) + (c & 3);
                    float z0  = zb[addr];
                    float z1v = zb[addr + 1];
                    zb[addr]     = fmaf(sc0, z0,  z0  + sh0);
                    zb[addr + 1] = fmaf(sc1, z1v, z1v + sh1);
                    float l01 = __logf(1.0f + sc0) + __logf(1.0f + sc1);
                    if (rt == 0) ldp0 += l01; else ldp1 += l01;
                }
            }
        }
        __syncthreads();

        // ---- reversal: z = z[:, ::-1] (logical f4-block pair swap); 256 tasks ----
        {
            int r = tid >> 3, cfL = tid & 7;
            int s = r & 7;
            float* pL = &zb[r*64 + ((cfL ^ s) << 2)];
            float* pR = &zb[r*64 + (((15 - cfL) ^ s) << 2)];
            f4 Lv = *(f4*)pL;
            f4 Rv = *(f4*)pR;
            f4 nL = { Rv[3], Rv[2], Rv[1], Rv[0] };
            f4 nR = { Lv[3], Lv[2], Lv[1], Lv[0] };
            *(f4*)pL = nL;
            *(f4*)pR = nR;
        }
    }
    __syncthreads();

    // ---- store z ----
    {
        f4* oz = (f4*)(out + (size_t)row0 * 64);
        #pragma unroll
        for (int q = 0; q < 2; ++q) {
            int idx4 = tid + q*256;
            int r = idx4 >> 4, cf = idx4 & 15;
            oz[idx4] = *(const f4*)&zb[r*64 + ((cf ^ (r & 7)) << 2)];
        }
    }

    // ---- logdet: reduce ldp over lg4 groups, combine 4 wave-slices via hbf scratch ----
    float* sc = (float*)hbf;   // h planes dead now; reuse as f32 scratch
    float v0 = ldp0 + __shfl_xor(ldp0, 16); v0 += __shfl_xor(v0, 32);
    float v1 = ldp1 + __shfl_xor(ldp1, 16); v1 += __shfl_xor(v1, 32);
    if (lg4 == 0) {
        sc[rA*4 + w] = v0;
        sc[rB*4 + w] = v1;
    }
    __syncthreads();
    if (tid < 32) {
        int gr = row0 + tid;
        out[(size_t)BB * 64 + gr] = logdet_in[gr] + lsum
                                  + sc[tid*4] + sc[tid*4+1] + sc[tid*4+2] + sc[tid*4+3];
    }
}

extern "C" void kernel_launch(void* const* d_in, const int* in_sizes, int n_in,
                              void* d_out, int out_size, void* d_ws, size_t ws_size,
                              hipStream_t stream)
{
    const float* x    = (const float*)d_in[0];
    const float* ld   = (const float*)d_in[1];
    const float* b    = (const float*)d_in[2];
    const float* logs = (const float*)d_in[3];
    const float* W1   = (const float*)d_in[4];
    const float* b1   = (const float*)d_in[5];
    const float* W2   = (const float*)d_in[6];
    const float* b2   = (const float*)d_in[7];
    const float* Wf   = (const float*)d_in[8];
    const float* bf   = (const float*)d_in[9];
    const float* lg   = (const float*)d_in[10];
    _Float16* wt = (_Float16*)d_ws;
    float* out = (float*)d_out;

    prep_weights<<<WTOT_F16 / 256, 256, 0, stream>>>(W1, W2, Wf, wt);
    flow_mfma<<<2048, 256, 0, stream>>>(x, ld, b, logs, b1, b2, bf, lg, wt, out);
}